// Round 8
// baseline (730.442 us; speedup 1.0000x reference)
//
#include <hip/hip_runtime.h>
#include <hip/hip_bf16.h>
#include <hip/hip_cooperative_groups.h>
#include <math.h>

namespace cg = cooperative_groups;

#define NCELL 512          // 8^3 cells
#define IMG_F 16384        // NCELL * 32 floats = 64 KB
#define NBLK  512          // cooperative grid: needs only 2 blocks/CU
#define THR   256

// ---------------------------------------------------------------------------
// conv phase as device function (blocks 0..255 active).
// lds: 72*36 floats staged 3x3-column periodic neighborhood (stride-36 pad)
// red2: 4*64 floats cross-part reduce.
// ---------------------------------------------------------------------------
__device__ inline void conv_phase(const float* __restrict__ in_lat,
                                  const float* __restrict__ w,
                                  float* __restrict__ out_lat,
                                  int act, int t, int bx,
                                  float* lds, float* red2)
{
    const int ixy = bx >> 2, qq = bx & 3;
    const int ix = ixy >> 3, iy = ixy & 7;

    for (int i = t; i < 576; i += THR) {
        const int cellL = i >> 3, c4 = i & 7;
        const int s9 = cellL >> 3, nz = cellL & 7;   // s9 = jx*3+jy
        const int jx = s9 / 3, jy = s9 - jx*3;
        const int gx = (ix + jx + 7) & 7, gy = (iy + jy + 7) & 7;
        const float4 v = ((const float4*)in_lat)[(gx*64 + gy*8 + nz)*8 + c4];
        *(float4*)&lds[cellL*36 + c4*4] = v;
    }
    __syncthreads();

    const int iz   = t & 7;
    const int co8  = (t >> 3) & 7;
    const int part = t >> 6;            // 0..3 tap subset
    const int cout = qq*8 + co8;

    float4 acc = {0.f,0.f,0.f,0.f};
    const int tau0 = (part * 27) >> 2, tau1 = ((part + 1) * 27) >> 2;
    for (int tau = tau0; tau < tau1; ++tau) {
        const int kd = tau / 9, r = tau - kd*9;
        const int kh = r / 3,  kw = r - kh*3;
        const int nz = (iz + kw + 7) & 7;
        const float* lrow = &lds[((kd*3 + kh)*8 + nz)*36];
        const float* wrow = &w[(size_t)(tau*32 + cout)*32];
        #pragma unroll
        for (int c4i = 0; c4i < 8; c4i++) {
            const float4 a = *(const float4*)(lrow + c4i*4);
            const float4 b = *(const float4*)(wrow + c4i*4);
            acc.x = fmaf(a.x, b.x, acc.x);
            acc.y = fmaf(a.y, b.y, acc.y);
            acc.z = fmaf(a.z, b.z, acc.z);
            acc.w = fmaf(a.w, b.w, acc.w);
        }
    }
    red2[part*64 + co8*8 + iz] = (acc.x + acc.y) + (acc.z + acc.w);
    __syncthreads();

    if (t < 64) {
        float s = red2[t] + red2[64 + t] + red2[128 + t] + red2[192 + t];
        const int oiz = t & 7, oco8 = t >> 3;
        const int oidx = (ix*64 + iy*8 + oiz)*32 + qq*8 + oco8;
        if (act) {
            const float r = in_lat[oidx];
            s = r + s / (1.f + expf(-s));    // r + silu(conv)
        }
        out_lat[oidx] = s;
    }
    __syncthreads();   // protect lds reuse by next phase
}

// ---------------------------------------------------------------------------
// Whole pipeline as ONE cooperative kernel. 512 blocks x 256 thr — needs only
// 2 blocks/CU co-resident (never at the cooperative occupancy boundary).
// ---------------------------------------------------------------------------
__global__ __launch_bounds__(THR, 2) void k_mega(
    const float* __restrict__ pos,
    const float* __restrict__ feat,
    const float* __restrict__ wenc,
    const float* __restrict__ winn,
    const float* __restrict__ wdec,
    float* __restrict__ out,
    int n,
    float4* __restrict__ meta,
    float*  __restrict__ Mbuf,
    float*  __restrict__ img,
    float*  __restrict__ h1,
    float*  __restrict__ h2,
    float*  __restrict__ olat,
    float*  __restrict__ aggb,
    int*    __restrict__ blockCnt,
    int*    __restrict__ relBase,
    int*    __restrict__ cellTot,
    int*    __restrict__ binStart)
{
    cg::grid_group grid = cg::this_grid();
    __shared__ __align__(16) unsigned char smem_raw[11392];  // union buffer
    int*   sh_i = (int*)smem_raw;
    float* sh_f = (float*)smem_raw;

    const int t  = threadIdx.x;
    const int bx = blockIdx.x;

    // ======================= P1: histogram =================================
    for (int i = t; i < NCELL; i += THR) sh_i[i] = 0;
    __syncthreads();
    for (int p = bx*THR + t; p < n; p += NBLK*THR) {
        const int ix = ((int)floorf(pos[3*p+0]*8.f)) & 7;
        const int iy = ((int)floorf(pos[3*p+1]*8.f)) & 7;
        const int iz = ((int)floorf(pos[3*p+2]*8.f)) & 7;
        atomicAdd(&sh_i[ix*64 + iy*8 + iz], 1);
    }
    __syncthreads();
    for (int i = t; i < NCELL; i += THR)
        blockCnt[bx*NCELL + i] = sh_i[i];
    grid.sync();

    // ======================= P2: per-cell scan over 512 hist rows ==========
    {
        const int c = bx;                     // every block owns one cell
        int v[2], pre[2], s = 0;
        #pragma unroll
        for (int j = 0; j < 2; j++) {
            v[j] = blockCnt[(t*2 + j)*NCELL + c];
            pre[j] = s; s += v[j];
        }
        __syncthreads();     // smem reuse boundary
        sh_i[t] = s;
        __syncthreads();
        int acc = s;
        for (int off = 1; off < THR; off <<= 1) {
            const int add = (t >= off) ? sh_i[t - off] : 0;
            __syncthreads();
            acc += add; sh_i[t] = acc;
            __syncthreads();
        }
        const int excl = acc - s;
        #pragma unroll
        for (int j = 0; j < 2; j++)
            relBase[(t*2 + j)*NCELL + c] = excl + pre[j];
        if (t == THR - 1) cellTot[c] = excl + s;
    }
    grid.sync();

    // ======================= P3: scan of 512 cell totals ===================
    if (bx == 0) {
        const int v0 = cellTot[2*t], v1 = cellTot[2*t + 1];
        const int s = v0 + v1;
        sh_i[t] = s;
        __syncthreads();
        int acc = s;
        for (int off = 1; off < THR; off <<= 1) {
            const int add = (t >= off) ? sh_i[t - off] : 0;
            __syncthreads();
            acc += add; sh_i[t] = acc;
            __syncthreads();
        }
        const int excl = acc - s;
        binStart[2*t]     = excl;
        binStart[2*t + 1] = excl + v0;
        if (t == THR - 1) binStart[NCELL] = excl + s;
    }
    grid.sync();

    // ======================= P4: reorder ==================================
    for (int i = t; i < NCELL; i += THR)
        sh_i[i] = binStart[i] + relBase[bx*NCELL + i];
    __syncthreads();
    for (int p = bx*THR + t; p < n; p += NBLK*THR) {
        const float sx = pos[3*p+0]*8.f, sy = pos[3*p+1]*8.f, sz = pos[3*p+2]*8.f;
        const float bxf = floorf(sx), byf = floorf(sy), bzf = floorf(sz);
        const int ix = ((int)bxf) & 7, iy = ((int)byf) & 7, iz = ((int)bzf) & 7;
        const int cell = ix*64 + iy*8 + iz;
        const int slot = atomicAdd(&sh_i[cell], 1);      // LDS ds_add_rtn
        meta[slot] = make_float4(sx - bxf, sy - byf, sz - bzf, __int_as_float(p));
    }
    grid.sync();

    // ======================= P5: accum (block = cell) =====================
    {
        const int cell = bx;
        const int c = t & 31, sub = t >> 5;              // sub 0..7
        const int s0 = binStart[cell], s1 = binStart[cell + 1];

        float acc[8];
        #pragma unroll
        for (int k = 0; k < 8; k++) acc[k] = 0.f;

        int i = s0 + sub;
        for (; i + 24 < s1; i += 32) {                   // batch-4 pipeline
            float4 m[4]; float v[4];
            #pragma unroll
            for (int j = 0; j < 4; j++) m[j] = meta[i + 8*j];
            #pragma unroll
            for (int j = 0; j < 4; j++)
                v[j] = feat[(size_t)__float_as_int(m[j].w) * 32 + c];
            #pragma unroll
            for (int j = 0; j < 4; j++) {
                const float gx = 1.f - m[j].x, gy = 1.f - m[j].y, gz = 1.f - m[j].z;
                const float a00 = gx*gy, a01 = gx*m[j].y, a10 = m[j].x*gy, a11 = m[j].x*m[j].y;
                acc[0] = fmaf(a00 * gz,     v[j], acc[0]);
                acc[1] = fmaf(a00 * m[j].z, v[j], acc[1]);
                acc[2] = fmaf(a01 * gz,     v[j], acc[2]);
                acc[3] = fmaf(a01 * m[j].z, v[j], acc[3]);
                acc[4] = fmaf(a10 * gz,     v[j], acc[4]);
                acc[5] = fmaf(a10 * m[j].z, v[j], acc[5]);
                acc[6] = fmaf(a11 * gz,     v[j], acc[6]);
                acc[7] = fmaf(a11 * m[j].z, v[j], acc[7]);
            }
        }
        for (; i < s1; i += 8) {                         // tail
            const float4 m = meta[i];
            const float v = feat[(size_t)__float_as_int(m.w) * 32 + c];
            const float gx = 1.f - m.x, gy = 1.f - m.y, gz = 1.f - m.z;
            const float a00 = gx*gy, a01 = gx*m.y, a10 = m.x*gy, a11 = m.x*m.y;
            acc[0] = fmaf(a00 * gz,  v, acc[0]);
            acc[1] = fmaf(a00 * m.z, v, acc[1]);
            acc[2] = fmaf(a01 * gz,  v, acc[2]);
            acc[3] = fmaf(a01 * m.z, v, acc[3]);
            acc[4] = fmaf(a10 * gz,  v, acc[4]);
            acc[5] = fmaf(a10 * m.z, v, acc[5]);
            acc[6] = fmaf(a11 * gz,  v, acc[6]);
            acc[7] = fmaf(a11 * m.z, v, acc[7]);
        }

        __syncthreads();     // smem reuse boundary
        #pragma unroll
        for (int k = 0; k < 8; k++) sh_f[sub*256 + k*32 + c] = acc[k];
        __syncthreads();
        const int k = t >> 5, cc = t & 31;
        float s = 0.f;
        #pragma unroll
        for (int ss = 0; ss < 8; ss++) s += sh_f[ss*256 + k*32 + cc];
        Mbuf[(cell*8 + k)*32 + cc] = s;                 // [cell][k][c]
    }
    grid.sync();

    // ======================= P6: flush -> img =============================
    {
        const int tid = bx*THR + t;
        if (tid < 4096) {
            const int cell = tid >> 3, c4 = tid & 7;
            const int x = cell >> 6, y = (cell >> 3) & 7, z = cell & 7;
            const float4* M4 = (const float4*)Mbuf;     // [512][8][8]
            float4 s = {0.f, 0.f, 0.f, 0.f};
            #pragma unroll
            for (int k = 0; k < 8; k++) {
                const int dx = (k >> 2) & 1, dy = (k >> 1) & 1, dz = k & 1;
                const int b = ((x - dx) & 7)*64 + ((y - dy) & 7)*8 + ((z - dz) & 7);
                const float4 v = M4[(b*8 + k)*8 + c4];
                s.x += v.x; s.y += v.y; s.z += v.z; s.w += v.w;
            }
            ((float4*)img)[tid] = s;
        }
    }
    grid.sync();

    // ======================= P7/8/9: conv chain ===========================
    {
        float* lds  = sh_f;
        float* red2 = sh_f + 72*36;
        if (bx < 256) conv_phase(img, wenc, h1, 0, t, bx, lds, red2);
        grid.sync();
        if (bx < 256) conv_phase(h1,  winn, h2, 1, t, bx, lds, red2);
        grid.sync();
        if (bx < 256) conv_phase(h2,  wdec, olat, 0, t, bx, lds, red2);
        grid.sync();
    }

    // ======================= P10: agg =====================================
    {
        const int tid = bx*THR + t;
        if (tid < 4096) {
            const int cell = tid >> 3, c4 = tid & 7;
            const int ix = cell >> 6, iy = (cell >> 3) & 7, iz = cell & 7;
            float4 s = {0.f,0.f,0.f,0.f};
            #pragma unroll
            for (int k = 0; k < 8; k++) {
                const int nx = (ix + ((k>>2)&1)) & 7;
                const int ny = (iy + ((k>>1)&1)) & 7;
                const int nz = (iz + (k&1)) & 7;
                const float4 v = ((const float4*)olat)[(nx*64 + ny*8 + nz)*8 + c4];
                s.x += v.x; s.y += v.y; s.z += v.z; s.w += v.w;
            }
            ((float4*)aggb)[tid] = s;
        }
    }
    grid.sync();

    // ======================= P11: gather ==================================
    {
        const int total = n * 8;
        for (int tid = bx*THR + t; tid < total; tid += NBLK*THR) {
            const int p = tid >> 3, c4 = tid & 7;
            const int ix = ((int)floorf(pos[3*p+0]*8.f)) & 7;
            const int iy = ((int)floorf(pos[3*p+1]*8.f)) & 7;
            const int iz = ((int)floorf(pos[3*p+2]*8.f)) & 7;
            ((float4*)out)[tid] = ((const float4*)aggb)[(ix*64 + iy*8 + iz)*8 + c4];
        }
    }
}

// ---------------------------------------------------------------------------
extern "C" void kernel_launch(void* const* d_in, const int* in_sizes, int n_in,
                              void* d_out, int out_size, void* d_ws, size_t ws_size,
                              hipStream_t stream)
{
    const float* pos  = (const float*)d_in[0];   // [N,3]
    const float* feat = (const float*)d_in[1];   // [N,32]
    const float* wenc = (const float*)d_in[2];   // [3,3,3,32,32]
    const float* winn = (const float*)d_in[3];   // [1,3,3,3,32,32]
    const float* wdec = (const float*)d_in[4];   // [3,3,3,32,32]
    float* out = (float*)d_out;
    int n = in_sizes[0] / 3;

    // ws layout (16B-aligned blocks first)
    float4* meta     = (float4*)d_ws;                       // n float4 (8 MB)
    float*  Mbuf     = (float*)(meta + n);                  // 512*8*32
    float*  img      = Mbuf + NCELL*8*32;
    float*  h1       = img  + IMG_F;
    float*  h2       = h1   + IMG_F;
    float*  olat     = h2   + IMG_F;
    float*  aggb     = olat + IMG_F;
    int*    blockCnt = (int*)(aggb + IMG_F);                // NBLK*NCELL (1MB)
    int*    relBase  = blockCnt + NBLK*NCELL;               // NBLK*NCELL (1MB)
    int*    cellTot  = relBase + NBLK*NCELL;                // 512
    int*    binStart = cellTot + NCELL;                     // 513

    void* args[] = {
        (void*)&pos, (void*)&feat, (void*)&wenc, (void*)&winn, (void*)&wdec,
        (void*)&out, (void*)&n,
        (void*)&meta, (void*)&Mbuf, (void*)&img, (void*)&h1, (void*)&h2,
        (void*)&olat, (void*)&aggb,
        (void*)&blockCnt, (void*)&relBase, (void*)&cellTot, (void*)&binStart
    };
    hipLaunchCooperativeKernel((void*)k_mega, dim3(NBLK), dim3(THR),
                               args, 0, stream);
}

// Round 9
// 177.615 us; speedup vs baseline: 4.1125x; 4.1125x over previous
//
#include <hip/hip_runtime.h>
#include <hip/hip_bf16.h>
#include <math.h>

#define NCELL 512          // 8^3 cells
#define IMG_F 16384        // NCELL * 32 floats = 64 KB
#define NB    256          // sort blocks (hist/reorder share this grid)
#define SPLIT 4            // accum blocks per cell

// ---------------------------------------------------------------------------
// K0: per-block histogram -> blockCnt[cell][b]   (no global atomics)
// ---------------------------------------------------------------------------
__global__ __launch_bounds__(256) void k_hist(
    const float* __restrict__ pos, int n, int* __restrict__ blockCnt)
{
    __shared__ int h[NCELL];
    const int t = threadIdx.x;
    for (int i = t; i < NCELL; i += 256) h[i] = 0;
    __syncthreads();
    const int stride = NB * 256;
    for (int p = blockIdx.x * 256 + t; p < n; p += stride) {
        const int ix = ((int)floorf(pos[3*p+0]*8.f)) & 7;
        const int iy = ((int)floorf(pos[3*p+1]*8.f)) & 7;
        const int iz = ((int)floorf(pos[3*p+2]*8.f)) & 7;
        atomicAdd(&h[ix*64 + iy*8 + iz], 1);
    }
    __syncthreads();
    for (int i = t; i < NCELL; i += 256)
        blockCnt[i * NB + blockIdx.x] = h[i];
}

// ---------------------------------------------------------------------------
// K0b: per-cell scan over the NB blocks. block = cell, thread = sort-block.
// ---------------------------------------------------------------------------
__global__ __launch_bounds__(NB) void k_colscan(
    const int* __restrict__ blockCnt,
    int* __restrict__ relBase,
    int* __restrict__ cellTot)
{
    __shared__ int s[NB];
    const int cell = blockIdx.x, b = threadIdx.x;
    const int v = blockCnt[cell * NB + b];     // coalesced
    s[b] = v;
    __syncthreads();
    int acc = v;
    for (int off = 1; off < NB; off <<= 1) {
        const int add = (b >= off) ? s[b - off] : 0;
        __syncthreads();
        acc += add;
        s[b] = acc;
        __syncthreads();
    }
    relBase[cell * NB + b] = acc - v;
    if (b == NB - 1) cellTot[cell] = acc;
}

// ---------------------------------------------------------------------------
// K0c: reorder. Each block locally scans cellTot (512 ints, LDS) to get
// binStart; block 0 also publishes binStart to global for k_accum (stream
// order guarantees visibility). Slots from LDS cursors; zero global atomics.
// Also writes cellIdx[p] (u16) so gather doesn't re-read pos.
// ---------------------------------------------------------------------------
__global__ __launch_bounds__(256) void k_reorder(
    const float* __restrict__ pos, int n,
    const int* __restrict__ relBase, const int* __restrict__ cellTot,
    int* __restrict__ binStart,
    float4* __restrict__ meta,
    unsigned short* __restrict__ cellIdx)
{
    __shared__ int sScan[256];
    __shared__ int cur[NCELL];
    const int t = threadIdx.x;
    const int bx = blockIdx.x;

    // local exclusive scan of 512 cell totals (pair-per-thread)
    const int v0 = cellTot[2*t], v1 = cellTot[2*t + 1];
    const int ps = v0 + v1;
    sScan[t] = ps;
    __syncthreads();
    int acc = ps;
    for (int off = 1; off < 256; off <<= 1) {
        const int add = (t >= off) ? sScan[t - off] : 0;
        __syncthreads();
        acc += add;
        sScan[t] = acc;
        __syncthreads();
    }
    const int exclPair = acc - ps;
    const int e0 = exclPair, e1 = exclPair + v0;
    if (bx == 0) {                      // publish for k_accum
        binStart[2*t]     = e0;
        binStart[2*t + 1] = e1;
        if (t == 255) binStart[NCELL] = acc;
    }
    cur[2*t]     = e0 + relBase[(2*t)     * NB + bx];
    cur[2*t + 1] = e1 + relBase[(2*t + 1) * NB + bx];
    __syncthreads();

    const int stride = NB * 256;
    for (int p = bx * 256 + t; p < n; p += stride) {
        const float sx = pos[3*p+0]*8.f, sy = pos[3*p+1]*8.f, sz = pos[3*p+2]*8.f;
        const float bxf = floorf(sx), byf = floorf(sy), bzf = floorf(sz);
        const int ix = ((int)bxf) & 7, iy = ((int)byf) & 7, iz = ((int)bzf) & 7;
        const int cell = ix*64 + iy*8 + iz;
        const int slot = atomicAdd(&cur[cell], 1);     // LDS ds_add_rtn
        meta[slot] = make_float4(sx - bxf, sy - byf, sz - bzf, __int_as_float(p));
        cellIdx[p] = (unsigned short)cell;
    }
}

// ---------------------------------------------------------------------------
// K1: per-(cell,split) register accumulation of M[8][32].
// grid = NCELL*SPLIT, 512 thr: c = t&31, sub = t>>5 (16 point subsets).
// Batch-4 load pipeline; __launch_bounds__(512,8) -> 32 waves/CU.
// ---------------------------------------------------------------------------
__global__ __launch_bounds__(512, 8) void k_accum(
    const float4* __restrict__ meta,
    const float* __restrict__ feat,
    const int* __restrict__ binStart,
    float* __restrict__ Mbuf)
{
    const int cell  = blockIdx.x >> 2;
    const int split = blockIdx.x & (SPLIT - 1);
    const int t = threadIdx.x;
    const int c = t & 31, sub = t >> 5;       // sub in 0..15
    const int b0 = binStart[cell], cnt = binStart[cell + 1] - b0;
    const int s0 = b0 + (cnt * split) / SPLIT;
    const int s1 = b0 + (cnt * (split + 1)) / SPLIT;

    float acc[8];
    #pragma unroll
    for (int k = 0; k < 8; k++) acc[k] = 0.f;

    int i = s0 + sub;
    for (; i + 48 < s1; i += 64) {            // batch-4 pipeline
        float4 m[4];
        float  v[4];
        #pragma unroll
        for (int j = 0; j < 4; j++) m[j] = meta[i + 16*j];
        #pragma unroll
        for (int j = 0; j < 4; j++)
            v[j] = feat[(size_t)__float_as_int(m[j].w) * 32 + c];
        #pragma unroll
        for (int j = 0; j < 4; j++) {
            const float gx = 1.f - m[j].x, gy = 1.f - m[j].y, gz = 1.f - m[j].z;
            const float a00 = gx*gy, a01 = gx*m[j].y, a10 = m[j].x*gy, a11 = m[j].x*m[j].y;
            acc[0] = fmaf(a00 * gz,     v[j], acc[0]);
            acc[1] = fmaf(a00 * m[j].z, v[j], acc[1]);
            acc[2] = fmaf(a01 * gz,     v[j], acc[2]);
            acc[3] = fmaf(a01 * m[j].z, v[j], acc[3]);
            acc[4] = fmaf(a10 * gz,     v[j], acc[4]);
            acc[5] = fmaf(a10 * m[j].z, v[j], acc[5]);
            acc[6] = fmaf(a11 * gz,     v[j], acc[6]);
            acc[7] = fmaf(a11 * m[j].z, v[j], acc[7]);
        }
    }
    for (; i < s1; i += 16) {                 // tail
        const float4 m = meta[i];
        const float v = feat[(size_t)__float_as_int(m.w) * 32 + c];
        const float gx = 1.f - m.x, gy = 1.f - m.y, gz = 1.f - m.z;
        const float a00 = gx*gy, a01 = gx*m.y, a10 = m.x*gy, a11 = m.x*m.y;
        acc[0] = fmaf(a00 * gz,  v, acc[0]);
        acc[1] = fmaf(a00 * m.z, v, acc[1]);
        acc[2] = fmaf(a01 * gz,  v, acc[2]);
        acc[3] = fmaf(a01 * m.z, v, acc[3]);
        acc[4] = fmaf(a10 * gz,  v, acc[4]);
        acc[5] = fmaf(a10 * m.z, v, acc[5]);
        acc[6] = fmaf(a11 * gz,  v, acc[6]);
        acc[7] = fmaf(a11 * m.z, v, acc[7]);
    }

    __shared__ float red[16 * 8 * 32];        // 16 KB
    #pragma unroll
    for (int k = 0; k < 8; k++) red[sub*256 + k*32 + c] = acc[k];
    __syncthreads();
    if (t < 256) {
        const int k = t >> 5, cc = t & 31;
        float s = 0.f;
        #pragma unroll
        for (int ss = 0; ss < 16; ss++) s += red[ss*256 + k*32 + cc];
        Mbuf[(blockIdx.x*8 + k)*32 + cc] = s;   // [cell][split][k][c]
    }
}

// ---------------------------------------------------------------------------
// K3: encoder conv with INLINE flush: stage lds[cellL] = sum_{k,sp} Mbuf[...]
// (Mbuf is 2MB, L2-resident; 8*SPLIT extra L2 reads per staged float4).
// Grid = 256 blocks: (ix,iy) x cout-octet. 512 thr = (iz 8)(co8 8)(part 8).
// ---------------------------------------------------------------------------
__global__ __launch_bounds__(512) void k_conv_enc(
    const float* __restrict__ Mbuf,
    const float* __restrict__ w,
    float* __restrict__ out_lat)
{
    __shared__ float lds[72*36];        // 10368 B
    __shared__ float red2[8*64];        // 2 KB
    const int t = threadIdx.x;
    const int ixy = blockIdx.x >> 2;
    const int qq  = blockIdx.x & 3;     // cout octet
    const int ix = ixy >> 3, iy = ixy & 7;
    const float4* M4 = (const float4*)Mbuf;   // [512][SPLIT][8][8]

    for (int i = t; i < 576; i += 512) {
        const int cellL = i >> 3, c4 = i & 7;
        const int s9 = cellL >> 3, nz = cellL & 7;   // s9 = jx*3+jy
        const int jx = s9 / 3, jy = s9 - jx*3;
        const int gx = (ix + jx + 7) & 7, gy = (iy + jy + 7) & 7;
        float4 s = {0.f,0.f,0.f,0.f};
        #pragma unroll
        for (int k = 0; k < 8; k++) {
            const int dx = (k >> 2) & 1, dy = (k >> 1) & 1, dz = k & 1;
            const int b = ((gx - dx) & 7)*64 + ((gy - dy) & 7)*8 + ((nz - dz) & 7);
            #pragma unroll
            for (int sp = 0; sp < SPLIT; sp++) {
                const float4 v = M4[((b*SPLIT + sp)*8 + k)*8 + c4];
                s.x += v.x; s.y += v.y; s.z += v.z; s.w += v.w;
            }
        }
        *(float4*)&lds[cellL*36 + c4*4] = s;
    }
    __syncthreads();

    const int iz   = t & 7;
    const int co8  = (t >> 3) & 7;
    const int part = t >> 6;            // 0..7 tap subset
    const int cout = qq*8 + co8;

    float4 acc = {0.f,0.f,0.f,0.f};
    const int tau0 = (part * 27) >> 3, tau1 = ((part + 1) * 27) >> 3;
    for (int tau = tau0; tau < tau1; ++tau) {
        const int kd = tau / 9, r = tau - kd*9;
        const int kh = r / 3,  kw = r - kh*3;
        const int nz = (iz + kw + 7) & 7;
        const float* lrow = &lds[((kd*3 + kh)*8 + nz)*36];
        const float* wrow = &w[(size_t)(tau*32 + cout)*32];
        #pragma unroll
        for (int c4i = 0; c4i < 8; c4i++) {
            const float4 a = *(const float4*)(lrow + c4i*4);
            const float4 b = *(const float4*)(wrow + c4i*4);
            acc.x = fmaf(a.x, b.x, acc.x);
            acc.y = fmaf(a.y, b.y, acc.y);
            acc.z = fmaf(a.z, b.z, acc.z);
            acc.w = fmaf(a.w, b.w, acc.w);
        }
    }
    red2[part*64 + co8*8 + iz] = (acc.x + acc.y) + (acc.z + acc.w);
    __syncthreads();

    if (t < 64) {
        const int oco8 = t >> 3, oiz = t & 7;
        float s = 0.f;
        #pragma unroll
        for (int pp = 0; pp < 8; pp++) s += red2[pp*64 + t];
        out_lat[(ix*64 + iy*8 + oiz)*32 + qq*8 + oco8] = s;
    }
}

// ---------------------------------------------------------------------------
// K4/K5: periodic 3x3x3 conv on a 64KB lattice (same structure as R6).
// ACT=0: out = conv(in).  ACT=1: out = in + silu(conv(in)).
// ---------------------------------------------------------------------------
template<int ACT>
__global__ __launch_bounds__(512) void k_conv(
    const float* __restrict__ in_lat,
    const float* __restrict__ w,
    float* __restrict__ out_lat)
{
    __shared__ float lds[72*36];
    __shared__ float red2[8*64];
    const int t = threadIdx.x;
    const int ixy = blockIdx.x >> 2;
    const int qq  = blockIdx.x & 3;
    const int ix = ixy >> 3, iy = ixy & 7;

    for (int i = t; i < 576; i += 512) {
        const int cellL = i >> 3, c4 = i & 7;
        const int s9 = cellL >> 3, nz = cellL & 7;
        const int jx = s9 / 3, jy = s9 - jx*3;
        const int gx = (ix + jx + 7) & 7, gy = (iy + jy + 7) & 7;
        const float4 v = ((const float4*)in_lat)[(gx*64 + gy*8 + nz)*8 + c4];
        *(float4*)&lds[cellL*36 + c4*4] = v;
    }
    __syncthreads();

    const int iz   = t & 7;
    const int co8  = (t >> 3) & 7;
    const int part = t >> 6;
    const int cout = qq*8 + co8;

    float4 acc = {0.f,0.f,0.f,0.f};
    const int tau0 = (part * 27) >> 3, tau1 = ((part + 1) * 27) >> 3;
    for (int tau = tau0; tau < tau1; ++tau) {
        const int kd = tau / 9, r = tau - kd*9;
        const int kh = r / 3,  kw = r - kh*3;
        const int nz = (iz + kw + 7) & 7;
        const float* lrow = &lds[((kd*3 + kh)*8 + nz)*36];
        const float* wrow = &w[(size_t)(tau*32 + cout)*32];
        #pragma unroll
        for (int c4i = 0; c4i < 8; c4i++) {
            const float4 a = *(const float4*)(lrow + c4i*4);
            const float4 b = *(const float4*)(wrow + c4i*4);
            acc.x = fmaf(a.x, b.x, acc.x);
            acc.y = fmaf(a.y, b.y, acc.y);
            acc.z = fmaf(a.z, b.z, acc.z);
            acc.w = fmaf(a.w, b.w, acc.w);
        }
    }
    red2[part*64 + co8*8 + iz] = (acc.x + acc.y) + (acc.z + acc.w);
    __syncthreads();

    if (t < 64) {
        const int oco8 = t >> 3, oiz = t & 7;
        float s = 0.f;
        #pragma unroll
        for (int pp = 0; pp < 8; pp++) s += red2[pp*64 + t];
        const int oidx = (ix*64 + iy*8 + oiz)*32 + qq*8 + oco8;
        if (ACT == 1) {
            const float rres = in_lat[oidx];
            s = rres + s / (1.f + expf(-s));    // r + silu(conv)
        }
        out_lat[oidx] = s;
    }
}

// ---------------------------------------------------------------------------
// K6: agg[cell] = sum over 8 corner-offset cells of out_lat
// ---------------------------------------------------------------------------
__global__ __launch_bounds__(256) void k_agg(
    const float* __restrict__ out_lat, float* __restrict__ agg)
{
    const int tid = blockIdx.x*256 + threadIdx.x;   // 0..4095
    if (tid >= 4096) return;
    const int cell = tid >> 3, c4 = tid & 7;
    const int ix = cell >> 6, iy = (cell >> 3) & 7, iz = cell & 7;
    float4 s = {0.f,0.f,0.f,0.f};
    #pragma unroll
    for (int k = 0; k < 8; k++) {
        const int nx = (ix + ((k>>2)&1)) & 7;
        const int ny = (iy + ((k>>1)&1)) & 7;
        const int nz = (iz + (k&1)) & 7;
        const float4 v = ((const float4*)out_lat)[(nx*64 + ny*8 + nz)*8 + c4];
        s.x += v.x; s.y += v.y; s.z += v.z; s.w += v.w;
    }
    ((float4*)agg)[tid] = s;
}

// ---------------------------------------------------------------------------
// K7: gather -- out[p] = agg[cellIdx[p]]  (1MB index read, not 6MB pos)
// ---------------------------------------------------------------------------
__global__ __launch_bounds__(256) void k_gather(
    const unsigned short* __restrict__ cellIdx,
    const float* __restrict__ agg,
    float* __restrict__ out,
    int n)
{
    const int tid = blockIdx.x*256 + threadIdx.x;   // over n*8
    const int p = tid >> 3, c4 = tid & 7;
    if (p >= n) return;
    const int cell = cellIdx[p];
    ((float4*)out)[tid] = ((const float4*)agg)[cell*8 + c4];
}

// ---------------------------------------------------------------------------
extern "C" void kernel_launch(void* const* d_in, const int* in_sizes, int n_in,
                              void* d_out, int out_size, void* d_ws, size_t ws_size,
                              hipStream_t stream)
{
    const float* pos  = (const float*)d_in[0];   // [N,3]
    const float* feat = (const float*)d_in[1];   // [N,32]
    const float* wenc = (const float*)d_in[2];   // [3,3,3,32,32]
    const float* winn = (const float*)d_in[3];   // [1,3,3,3,32,32]
    const float* wdec = (const float*)d_in[4];   // [3,3,3,32,32]
    float* out = (float*)d_out;
    const int n = in_sizes[0] / 3;

    // ws layout (16B-aligned blocks first)
    float4* meta     = (float4*)d_ws;                       // n float4 (8 MB)
    float*  Mbuf     = (float*)(meta + n);                  // 512*SPLIT*8*32 (2 MB)
    float*  h1       = Mbuf + NCELL*SPLIT*8*32;
    float*  h2       = h1   + IMG_F;
    float*  olat     = h2   + IMG_F;
    float*  aggb     = olat + IMG_F;
    int*    blockCnt = (int*)(aggb + IMG_F);                // NCELL*NB
    int*    relBase  = blockCnt + NCELL*NB;                 // NCELL*NB
    int*    cellTot  = relBase + NCELL*NB;                  // 512
    int*    binStart = cellTot + NCELL;                     // 513
    unsigned short* cellIdx = (unsigned short*)(binStart + NCELL + 3); // n u16

    k_hist    <<<NB,    256, 0, stream>>>(pos, n, blockCnt);
    k_colscan <<<NCELL, NB,  0, stream>>>(blockCnt, relBase, cellTot);
    k_reorder <<<NB,    256, 0, stream>>>(pos, n, relBase, cellTot, binStart,
                                          meta, cellIdx);
    k_accum   <<<NCELL*SPLIT, 512, 0, stream>>>(meta, feat, binStart, Mbuf);
    k_conv_enc<<<256,   512, 0, stream>>>(Mbuf, wenc, h1);
    k_conv<1> <<<256,   512, 0, stream>>>(h1,  winn, h2);
    k_conv<0> <<<256,   512, 0, stream>>>(h2,  wdec, olat);
    k_agg     <<<16,    256, 0, stream>>>(olat, aggb);
    const int gblocks = (n*8 + 255)/256;
    k_gather  <<<gblocks, 256, 0, stream>>>(cellIdx, aggb, out, n);
}